// Round 2
// baseline (176.114 us; speedup 1.0000x reference)
//
#include <hip/hip_runtime.h>

#define BINS 4096   // 16^3
#define GRID 256
#define BLOCK 512

__device__ __forceinline__ int qz(float c) {
    // matches: clip((c * 15.0f).astype(int32), 0, 15); trunc == floor for c >= 0
    int q = (int)(c * 15.0f);
    q = q < 0 ? 0 : q;
    q = q > 15 ? 15 : q;
    return q;
}

__device__ __forceinline__ int bin3(float r, float g, float b) {
    return (qz(r) << 8) | (qz(g) << 4) | qz(b);
}

// Fused: per-block LDS histogram of source -> rotated global-atomic flush ->
// last block (completion counter) builds target hist in LDS and computes loss.
__global__ __launch_bounds__(BLOCK) void fused_hist_loss_kernel(
        const float* __restrict__ src, const float* __restrict__ tgt,
        unsigned int* __restrict__ g_hist, unsigned int* __restrict__ counter,
        float* __restrict__ out, int n_src, int n_tgt) {
    __shared__ unsigned int lhist[BINS];
    for (int i = threadIdx.x; i < BINS; i += BLOCK) lhist[i] = 0;
    __syncthreads();

    // ---- source histogram: 4 points per iter via 3x float4 (16 B/lane) ----
    const float4* __restrict__ src4 = (const float4*)src;
    const int n_quads = n_src >> 2;
    const int tid = blockIdx.x * BLOCK + threadIdx.x;
    const int stride = gridDim.x * BLOCK;
    for (int q = tid; q < n_quads; q += stride) {
        float4 a = src4[3 * q + 0];
        float4 b = src4[3 * q + 1];
        float4 c = src4[3 * q + 2];
        atomicAdd(&lhist[bin3(a.x, a.y, a.z)], 1u);
        atomicAdd(&lhist[bin3(a.w, b.x, b.y)], 1u);
        atomicAdd(&lhist[bin3(b.z, b.w, c.x)], 1u);
        atomicAdd(&lhist[bin3(c.y, c.z, c.w)], 1u);
    }
    if (blockIdx.x == 0) {
        int tail = n_src & 3;
        if ((int)threadIdx.x < tail) {
            int p = (n_quads << 2) + threadIdx.x;
            atomicAdd(&lhist[bin3(src[3 * p], src[3 * p + 1], src[3 * p + 2])], 1u);
        }
    }
    __syncthreads();

    // ---- flush to global, rotated start so blocks don't hot-spot same bin ----
    const int rot = (blockIdx.x * 64) & (BINS - 1);
    for (int k = threadIdx.x; k < BINS; k += BLOCK) {
        int i = (k + rot) & (BINS - 1);
        unsigned int v = lhist[i];
        if (v) atomicAdd(&g_hist[i], v);
    }

    // ---- completion counter: last block to finish computes the loss ----
    __threadfence();
    __syncthreads();
    __shared__ int is_last;
    if (threadIdx.x == 0) {
        unsigned int prev = atomicAdd(counter, 1u);
        is_last = (prev == (unsigned int)(gridDim.x - 1)) ? 1 : 0;
    }
    __syncthreads();
    if (!is_last) return;

    // ---- last block: target histogram into reused LDS ----
    for (int i = threadIdx.x; i < BINS; i += BLOCK) lhist[i] = 0;
    __syncthreads();
    const float4* __restrict__ t4 = (const float4*)tgt;
    const int tq = n_tgt >> 2;
    for (int q = threadIdx.x; q < tq; q += BLOCK) {
        float4 a = t4[3 * q + 0];
        float4 b = t4[3 * q + 1];
        float4 c = t4[3 * q + 2];
        atomicAdd(&lhist[bin3(a.x, a.y, a.z)], 1u);
        atomicAdd(&lhist[bin3(a.w, b.x, b.y)], 1u);
        atomicAdd(&lhist[bin3(b.z, b.w, c.x)], 1u);
        atomicAdd(&lhist[bin3(c.y, c.z, c.w)], 1u);
    }
    {
        int tail = n_tgt & 3;
        if ((int)threadIdx.x < tail) {
            int p = (tq << 2) + threadIdx.x;
            atomicAdd(&lhist[bin3(tgt[3 * p], tgt[3 * p + 1], tgt[3 * p + 2])], 1u);
        }
    }
    __syncthreads();

    // ---- L1 loss between normalized histograms (f64 accumulation) ----
    const double ns = (double)n_src + 1e-8;
    const double nt = (double)n_tgt + 1e-8;
    double acc = 0.0;
    for (int i = threadIdx.x; i < BINS; i += BLOCK) {
        unsigned int sv = atomicAdd(&g_hist[i], 0u);  // device-coherent load
        double s = (double)sv / ns;
        double t = (double)lhist[i] / nt;
        acc += fabs(s - t);
    }
    for (int off = 32; off > 0; off >>= 1) acc += __shfl_down(acc, off);
    __shared__ double red[BLOCK / 64];
    const int lane = threadIdx.x & 63;
    const int wave = threadIdx.x >> 6;
    if (lane == 0) red[wave] = acc;
    __syncthreads();
    if (threadIdx.x == 0) {
        double s = 0.0;
        for (int w = 0; w < BLOCK / 64; ++w) s += red[w];
        out[0] = (float)(s / (double)BINS);
    }
}

extern "C" void kernel_launch(void* const* d_in, const int* in_sizes, int n_in,
                              void* d_out, int out_size, void* d_ws, size_t ws_size,
                              hipStream_t stream) {
    const float* src = (const float*)d_in[0];
    const float* tgt = (const float*)d_in[1];
    const int n_src = in_sizes[0] / 3;
    const int n_tgt = in_sizes[1] / 3;

    unsigned int* g_hist = (unsigned int*)d_ws;      // 4096 u32 = 16 KB
    unsigned int* counter = g_hist + BINS;           // +1 u32

    hipMemsetAsync(d_ws, 0, (BINS + 16) * sizeof(unsigned int), stream);
    fused_hist_loss_kernel<<<GRID, BLOCK, 0, stream>>>(
        src, tgt, g_hist, counter, (float*)d_out, n_src, n_tgt);
}